// Round 1
// baseline (687.467 us; speedup 1.0000x reference)
//
#include <hip/hip_runtime.h>

#define Bdim 16
#define Cdim 512
#define Hdim 128
#define Wdim 128
#define NS 8
// per channel: H*W = 16384 floats; per thread: 64 floats = 16 float4

__global__ __launch_bounds__(256) void chan_reduce(const float* __restrict__ x,
                                                   int* __restrict__ rc,
                                                   float* __restrict__ F) {
    const int bid = blockIdx.x;          // b*C + c
    const int tid = threadIdx.x;
    const float4* __restrict__ p = (const float4*)(x + ((size_t)bid << 14));

    float4 r[16];
    float tmax = -INFINITY;
    float tsum = 0.f;
#pragma unroll
    for (int i = 0; i < 16; ++i) {
        r[i] = p[i * 256 + tid];
        tsum += (r[i].x + r[i].y) + (r[i].z + r[i].w);
        tmax = fmaxf(tmax, fmaxf(fmaxf(r[i].x, r[i].y), fmaxf(r[i].z, r[i].w)));
    }

    // wave (64-lane) reduction
#pragma unroll
    for (int off = 32; off > 0; off >>= 1) {
        tsum += __shfl_down(tsum, off, 64);
        tmax = fmaxf(tmax, __shfl_down(tmax, off, 64));
    }

    __shared__ float smax[4], ssum[4];
    const int wave = tid >> 6;
    if ((tid & 63) == 0) { smax[wave] = tmax; ssum[wave] = tsum; }
    __syncthreads();

    const float bmax = fmaxf(fmaxf(smax[0], smax[1]), fmaxf(smax[2], smax[3]));
    if (tid == 0) {
        F[bid] = (ssum[0] + ssum[1] + ssum[2] + ssum[3]) * (1.0f / Wdim);
    }

    // count elements equal to channel max, per row.
    // thread's float4 #i lives in row i*8 + (tid>>5)
    const int b = bid >> 9;              // bid / Cdim
    const int rsub = tid >> 5;
#pragma unroll
    for (int i = 0; i < 16; ++i) {
        int cnt = (r[i].x == bmax) + (r[i].y == bmax) +
                  (r[i].z == bmax) + (r[i].w == bmax);
        if (cnt) atomicAdd(&rc[b * Hdim + i * 8 + rsub], cnt);
    }
}

__global__ __launch_bounds__(256) void finalize(const int* __restrict__ rc,
                                                const float* __restrict__ F,
                                                float* __restrict__ out) {
    const int b = blockIdx.x;
    const int tid = threadIdx.x;
    __shared__ int s_rc[Hdim];
    __shared__ int s_Hc[Hdim + 1];
    __shared__ float s_sub[NS];

    if (tid < Hdim) s_rc[tid] = rc[b * Hdim + tid];
    __syncthreads();

    if (tid == 0) {
        s_Hc[0] = 0;
        for (int i = 1; i <= Hdim; ++i) s_Hc[i] = s_Hc[i - 1] + s_rc[i - 1];
        float hks[NS + 1];
        for (int k = 0; k <= NS; ++k) hks[k] = 0.f;
        hks[NS] = (float)Hdim;
        int k = 1;
        for (int j = 1; j <= Hdim - 2; ++j) {
            int t = (k * Cdim) / NS;  // int(k*C/ns)
            if (k < NS && s_Hc[j] <= t && s_Hc[j + 1] > t) {
                hks[k] = (float)j;
                ++k;
            }
        }
        for (int q = 0; q < NS; ++q) s_sub[q] = hks[q + 1] - hks[q];
    }
    __syncthreads();

    // out[b, k*C + c] = F[b, c] / hk_sub[b, k]
    for (int idx = tid; idx < NS * Cdim; idx += 256) {
        int k = idx >> 9;          // idx / Cdim
        int c = idx & (Cdim - 1);
        out[b * (NS * Cdim) + idx] = F[b * Cdim + c] / s_sub[k];
    }
}

extern "C" void kernel_launch(void* const* d_in, const int* in_sizes, int n_in,
                              void* d_out, int out_size, void* d_ws, size_t ws_size,
                              hipStream_t stream) {
    const float* x = (const float*)d_in[0];
    float* out = (float*)d_out;
    int* rc = (int*)d_ws;                                         // B*H ints (8 KB)
    float* F = (float*)((char*)d_ws + Bdim * Hdim * sizeof(int)); // B*C floats (32 KB)

    hipMemsetAsync(rc, 0, Bdim * Hdim * sizeof(int), stream);
    chan_reduce<<<Bdim * Cdim, 256, 0, stream>>>(x, rc, F);
    finalize<<<Bdim, 256, 0, stream>>>(rc, F, out);
}